// Round 22
// baseline (221.745 us; speedup 1.0000x reference)
//
#include <hip/hip_runtime.h>
#include <hip/hip_bf16.h>

typedef __attribute__((ext_vector_type(4))) float f32x4;
typedef __attribute__((ext_vector_type(4))) int   int4v;
typedef __attribute__((ext_vector_type(2))) int   int2v;
typedef __attribute__((ext_vector_type(16))) int  i32x16;

#define N_NBR 65536
#define INIT_DIM 512
#define HID 1024
#define NTILE 3072     // 3 types x 1024 tiles (64 rows each)
#define SA 24.0f       // activation scale
#define SW 1024.0f     // weight scale
#define INVS (1.0f / (24.0f * 1024.0f))

static __device__ __forceinline__ int q8(float x, float s) {
  float y = fminf(fmaxf(x * s, -127.f), 127.f);
  return __float2int_rn(y);
}
static __device__ __forceinline__ int pack4(float a, float b, float c, float d, float s) {
  return (q8(a,s) & 255) | ((q8(b,s) & 255) << 8) | ((q8(c,s) & 255) << 16) | ((q8(d,s) & 255) << 24);
}

// Relayout W (3x [1024 n][512 k] f32) -> i8 fragments for mfma_i32_32x32x32_i8.
__global__ __launch_bounds__(256) void k_convw(const float* __restrict__ wa,
                                               const float* __restrict__ wb,
                                               const float* __restrict__ wc,
                                               char* __restrict__ out) {
  int g = blockIdx.x * 256 + threadIdx.x;   // 0..98303
  int l = g & 63;
  int blk = g >> 6;           // t*512 + nb*16 + ks
  int ks = blk & 15;
  int nb = (blk >> 4) & 31;
  int t = blk >> 9;
  const float* src = (t == 0) ? wa : (t == 1) ? wb : wc;
  int n = nb * 32 + (l & 31);
  int k0 = ks * 32 + (l >> 5) * 16;
  const f32x4* p = (const f32x4*)(src + (size_t)n * INIT_DIM + k0);
  f32x4 x0 = p[0], x1 = p[1], x2 = p[2], x3 = p[3];
  int4v v;
  v[0] = pack4(x0.x, x0.y, x0.z, x0.w, SW);
  v[1] = pack4(x1.x, x1.y, x1.z, x1.w, SW);
  v[2] = pack4(x2.x, x2.y, x2.z, x2.w, SW);
  v[3] = pack4(x3.x, x3.y, x3.z, x3.w, SW);
  *(int4v*)(out + (size_t)g * 16) = v;
}

// SPLIT kernel A: pure streaming gather+quant. Writes dense PRE-SWIZZLED
// 32KB i8 tiles to ws (rule #21: swizzle baked into source ordering so the
// GEMM kernel copies linearly and reads swizzled). No LDS, no barrier,
// tiny VGPR -> high occupancy; single-regime memory kernel.
__global__ __launch_bounds__(256) void k_gather(
    const float* __restrict__ fa, const float* __restrict__ fb, const float* __restrict__ fc,
    const int* __restrict__ na, const int* __restrict__ nb_, const int* __restrict__ nc__,
    char* __restrict__ aq) {                  // [NTILE][32768]
  int bx = blockIdx.x;
  int t = bx >> 10;
  int mtile = bx & 1023;
  const float* feat = (t == 0) ? fa : (t == 1) ? fb : fc;
  const int*   nbr  = (t == 0) ? na : (t == 1) ? nb_ : nc__;
  int tid = threadIdx.x;
  int wave = tid >> 6;
  int lane = tid & 63;
  char* outt = aq + (size_t)bx * 32768;
  #pragma unroll 4
  for (int c = 0; c < 16; ++c) {
    int r = c * 4 + wave;
    int idx = nbr[mtile * 64 + r];            // wave-uniform -> scalar load
    const float* rp = feat + (size_t)idx * INIT_DIM + lane * 8;
    f32x4 a  = *(const f32x4*)rp;
    f32x4 b2 = *((const f32x4*)rp + 1);
    int2v v;
    v[0] = pack4(a.x, a.y, a.z, a.w, SA);
    v[1] = pack4(b2.x, b2.y, b2.z, b2.w, SA);
    unsigned byte = (unsigned)r * 512u +
                    (((unsigned)lane * 8u) ^ ((unsigned)(r & 31) << 4));
    *(int2v*)(outt + byte) = v;               // 512B span per wave, permuted
  }
}

// SPLIT kernel B: GEMM only. Stage = 8 coalesced 16B copies/thread from the
// pre-swizzled ws tile (no quant VALU, no f32 holds), then R17's proven
// K-loop (mf=2 nf=2, 64 AGPR, 0-conflict swizzled reads) + int epilogue.
__global__ __launch_bounds__(256) void k_main_split(
    const char* __restrict__ aq,              // [NTILE][32768] pre-swizzled i8
    const float* __restrict__ b1a, const float* __restrict__ b1b, const float* __restrict__ b1c,
    const char* __restrict__ wbf8,            // [3][32 nb][16 ks][1024B] i8 fragments
    float* __restrict__ partials) {           // [NTILE][HID]
  __shared__ __align__(16) char Asm[64 * 512];   // 32 KB

  int bx = blockIdx.x;
  int t = bx >> 10;
  const float* bias = (t == 0) ? b1a : (t == 1) ? b1b : b1c;
  const char*  Wf8  = wbf8 + (size_t)t * (32 * 16 * 1024);

  int tid = threadIdx.x;
  int wave = tid >> 6;
  int lane = tid & 63;
  int l31 = lane & 31, hi = lane >> 5;

  // Linear tile copy: ws bytes ARE the swizzled layout.
  {
    const int4v* srcv = (const int4v*)(aq + (size_t)bx * 32768);
    int4v* dstv = (int4v*)Asm;
    #pragma unroll 4
    for (int k = 0; k < 8; ++k)
      dstv[k * 256 + tid] = srcv[k * 256 + tid];
  }
  __syncthreads();

  unsigned swz = (unsigned)l31 << 4;
  unsigned abase = (unsigned)l31 * 512u + (((unsigned)hi << 4) ^ (swz & 16u));
  unsigned swzhi = swz & 0x1E0u;

  #pragma unroll
  for (int p = 0; p < 4; ++p) {
    const char* pBa = Wf8 + ((size_t)(wave * 8 + p * 2)     << 14) + lane * 16;
    const char* pBb = Wf8 + ((size_t)(wave * 8 + p * 2 + 1) << 14) + lane * 16;

    i32x16 acc[2][2] = {};   // [mf][nf] -> 64 AGPR
    #pragma unroll 4
    for (int ks = 0; ks < 16; ++ks) {
      int4v Bf0 = *(const int4v*)(pBa + (ks << 10));
      int4v Bf1 = *(const int4v*)(pBb + (ks << 10));
      unsigned kcol = (((unsigned)ks << 5) ^ swzhi);
      int4v Af[2];
      #pragma unroll
      for (int i = 0; i < 2; ++i)
        Af[i] = *(const int4v*)(Asm + (abase + (unsigned)(i * 16384) + kcol));
      #pragma unroll
      for (int i = 0; i < 2; ++i) {
        acc[i][0] = __builtin_amdgcn_mfma_i32_32x32x32_i8(Af[i], Bf0, acc[i][0], 0, 0, 0);
        acc[i][1] = __builtin_amdgcn_mfma_i32_32x32x32_i8(Af[i], Bf1, acc[i][1], 0, 0, 0);
      }
    }

    #pragma unroll
    for (int j = 0; j < 2; ++j) {
      int n = (wave * 8 + p * 2 + j) * 32 + l31;
      int bq = __float2int_rn(bias[n] * (SA * SW));
      int s = 0;
      #pragma unroll
      for (int i = 0; i < 2; ++i)
        #pragma unroll
        for (int r = 0; r < 16; ++r)
          s += max(acc[i][j][r] + bq, 0);
      s += __shfl_xor(s, 32);
      if (hi == 0) partials[(size_t)bx * HID + n] = (float)s * INVS;
    }
  }
}

// FALLBACK (R17 fused, best-known-good) if ws_size can't hold aq.
__global__ __launch_bounds__(256) void k_main_fused(
    const float* __restrict__ fa, const float* __restrict__ fb, const float* __restrict__ fc,
    const int* __restrict__ na, const int* __restrict__ nb_, const int* __restrict__ nc__,
    const float* __restrict__ b1a, const float* __restrict__ b1b, const float* __restrict__ b1c,
    const char* __restrict__ wbf8,
    float* __restrict__ partials) {
  __shared__ __align__(16) char Asm[64 * 512];
  int bx = blockIdx.x;
  int t = bx >> 10;
  int mtile = bx & 1023;
  const float* feat = (t == 0) ? fa : (t == 1) ? fb : fc;
  const int*   nbr  = (t == 0) ? na : (t == 1) ? nb_ : nc__;
  const float* bias = (t == 0) ? b1a : (t == 1) ? b1b : b1c;
  const char*  Wf8  = wbf8 + (size_t)t * (32 * 16 * 1024);
  int tid = threadIdx.x;
  int wave = tid >> 6;
  int lane = tid & 63;
  int l31 = lane & 31, hi = lane >> 5;
  #pragma unroll 2
  for (int c = 0; c < 16; ++c) {
    int r = c * 4 + wave;
    int idx = nbr[mtile * 64 + r];
    const float* rp = feat + (size_t)idx * INIT_DIM + lane * 8;
    f32x4 a  = *(const f32x4*)rp;
    f32x4 b2 = *((const f32x4*)rp + 1);
    int2v v;
    v[0] = pack4(a.x, a.y, a.z, a.w, SA);
    v[1] = pack4(b2.x, b2.y, b2.z, b2.w, SA);
    unsigned byte = (unsigned)r * 512u +
                    (((unsigned)lane * 8u) ^ ((unsigned)(r & 31) << 4));
    *(int2v*)(Asm + byte) = v;
  }
  __syncthreads();
  unsigned swz = (unsigned)l31 << 4;
  unsigned abase = (unsigned)l31 * 512u + (((unsigned)hi << 4) ^ (swz & 16u));
  unsigned swzhi = swz & 0x1E0u;
  #pragma unroll
  for (int p = 0; p < 4; ++p) {
    const char* pBa = Wf8 + ((size_t)(wave * 8 + p * 2)     << 14) + lane * 16;
    const char* pBb = Wf8 + ((size_t)(wave * 8 + p * 2 + 1) << 14) + lane * 16;
    i32x16 acc[2][2] = {};
    #pragma unroll 4
    for (int ks = 0; ks < 16; ++ks) {
      int4v Bf0 = *(const int4v*)(pBa + (ks << 10));
      int4v Bf1 = *(const int4v*)(pBb + (ks << 10));
      unsigned kcol = (((unsigned)ks << 5) ^ swzhi);
      int4v Af[2];
      #pragma unroll
      for (int i = 0; i < 2; ++i)
        Af[i] = *(const int4v*)(Asm + (abase + (unsigned)(i * 16384) + kcol));
      #pragma unroll
      for (int i = 0; i < 2; ++i) {
        acc[i][0] = __builtin_amdgcn_mfma_i32_32x32x32_i8(Af[i], Bf0, acc[i][0], 0, 0, 0);
        acc[i][1] = __builtin_amdgcn_mfma_i32_32x32x32_i8(Af[i], Bf1, acc[i][1], 0, 0, 0);
      }
    }
    #pragma unroll
    for (int j = 0; j < 2; ++j) {
      int n = (wave * 8 + p * 2 + j) * 32 + l31;
      int bq = __float2int_rn(bias[n] * (SA * SW));
      int s = 0;
      #pragma unroll
      for (int i = 0; i < 2; ++i)
        #pragma unroll
        for (int r = 0; r < 16; ++r)
          s += max(acc[i][j][r] + bq, 0);
      s += __shfl_xor(s, 32);
      if (hi == 0) partials[(size_t)bx * HID + n] = (float)s * INVS;
    }
  }
}

// Reduce stage 1: coalesced f32x4 sums of 16-row slabs -> inter[192][1024].
__global__ __launch_bounds__(256) void k_reduce1(const float* __restrict__ partials,
                                                 float* __restrict__ inter) {
  int b = blockIdx.x;
  int tid = threadIdx.x;
  const f32x4* base = (const f32x4*)(partials + (size_t)b * 16 * HID) + tid;
  f32x4 s = {0.f, 0.f, 0.f, 0.f};
  #pragma unroll 4
  for (int r = 0; r < 16; ++r) {
    f32x4 v = base[r * (HID / 4)];
    s.x += v.x; s.y += v.y; s.z += v.z; s.w += v.w;
  }
  *((f32x4*)(inter + (size_t)b * HID) + tid) = s;
}

// Reduce stage 2: one 1024-thread block, col per thread.
__global__ __launch_bounds__(1024) void k_reduce2(const float* __restrict__ inter,
                                                  float* __restrict__ acc) {
  int col = threadIdx.x;
  float s = 0.f;
  #pragma unroll 8
  for (int r = 0; r < 192; ++r) s += inter[(size_t)r * HID + col];
  acc[col] = s;
}

// pooled = acc/196608 ; feat_all = relu ; logits = feat_all @ Wc.T + bc
__global__ __launch_bounds__(256) void k_final(const float* __restrict__ acc,
                                               const float* __restrict__ Wc,
                                               const float* __restrict__ bc,
                                               float* __restrict__ out) {
  __shared__ float fall[HID];
  int tid = threadIdx.x;
  const float inv = 1.f / (3.f * (float)N_NBR);
  for (int i = tid; i < HID; i += 256) {
    float p = acc[i] * inv;
    fall[i] = (p > 0.f) ? p : 0.f;
  }
  __syncthreads();
  int o = tid >> 2, q = tid & 3;
  const f32x4* w = (const f32x4*)(Wc + (size_t)o * HID + q * 256);
  const f32x4* f = (const f32x4*)(fall + q * 256);
  float s = 0.f;
  #pragma unroll 4
  for (int k = 0; k < 64; ++k) {
    f32x4 wv = w[k], fv = f[k];
    s += wv.x * fv.x + wv.y * fv.y + wv.z * fv.z + wv.w * fv.w;
  }
  s += __shfl_xor(s, 1);
  s += __shfl_xor(s, 2);
  if (q == 0) out[o] = s + bc[o];
}

extern "C" void kernel_launch(void* const* d_in, const int* in_sizes, int n_in,
                              void* d_out, int out_size, void* d_ws, size_t ws_size,
                              hipStream_t stream) {
  const float* fa  = (const float*)d_in[1];
  const int*   na  = (const int*)d_in[2];
  const float* W1a = (const float*)d_in[3];
  const float* b1a = (const float*)d_in[4];
  const float* fb  = (const float*)d_in[5];
  const int*   nb  = (const int*)d_in[6];
  const float* W1b = (const float*)d_in[7];
  const float* b1b = (const float*)d_in[8];
  const float* fc  = (const float*)d_in[9];
  const int*   nc  = (const int*)d_in[10];
  const float* W1c = (const float*)d_in[11];
  const float* b1c = (const float*)d_in[12];
  const float* Wc  = (const float*)d_in[13];
  const float* bc  = (const float*)d_in[14];
  float* out = (float*)d_out;

  const size_t wbf8_off = 4096;
  const size_t wbf8_sz  = 3 * 32 * 16 * 1024;            // 1.5 MB
  const size_t aq_sz    = (size_t)NTILE * 32768;         // 96 MB
  const size_t part_sz  = (size_t)NTILE * HID * 4;       // 12.6 MB
  const size_t inter_sz = 192 * HID * 4;                 // 768 KB

  float* acc = (float*)d_ws;
  char*  wbf8 = (char*)d_ws + wbf8_off;
  size_t need_split = wbf8_off + wbf8_sz + aq_sz + part_sz + inter_sz;

  k_convw<<<384, 256, 0, stream>>>(W1a, W1b, W1c, wbf8);

  if (ws_size >= need_split) {
    char*  aq = wbf8 + wbf8_sz;
    float* partials = (float*)(aq + aq_sz);
    float* inter = partials + (size_t)NTILE * HID;
    k_gather<<<NTILE, 256, 0, stream>>>(fa, fb, fc, na, nb, nc, aq);
    k_main_split<<<NTILE, 256, 0, stream>>>(aq, b1a, b1b, b1c, wbf8, partials);
    k_reduce1<<<192, 256, 0, stream>>>(partials, inter);
    k_reduce2<<<1, 1024, 0, stream>>>(inter, acc);
  } else {
    float* partials = (float*)(wbf8 + wbf8_sz);
    float* inter = partials + (size_t)NTILE * HID;
    k_main_fused<<<NTILE, 256, 0, stream>>>(fa, fb, fc, na, nb, nc, b1a, b1b, b1c, wbf8, partials);
    k_reduce1<<<192, 256, 0, stream>>>(partials, inter);
    k_reduce2<<<1, 1024, 0, stream>>>(inter, acc);
  }
  k_final<<<1, 256, 0, stream>>>(acc, Wc, bc, out);
}

// Round 23
// 201.558 us; speedup vs baseline: 1.1002x; 1.1002x over previous
//
#include <hip/hip_runtime.h>
#include <hip/hip_bf16.h>

typedef __attribute__((ext_vector_type(4))) float f32x4;
typedef __attribute__((ext_vector_type(4))) int   int4v;
typedef __attribute__((ext_vector_type(2))) int   int2v;
typedef __attribute__((ext_vector_type(16))) int  i32x16;

#define N_NODES 100000
#define N_NBR 65536
#define INIT_DIM 512
#define HID 1024
#define NTILE 3072     // 3 types x 1024 tile slots (64 rows each; tail slots empty)
#define NBLK_SC 391    // ceil(100000/256) blocks per type for scan kernels
#define SA 24.0f
#define SW 1024.0f
#define INVS (1.0f / (24.0f * 1024.0f))

static __device__ __forceinline__ int q8(float x, float s) {
  float y = fminf(fmaxf(x * s, -127.f), 127.f);
  return __float2int_rn(y);
}
static __device__ __forceinline__ int pack4(float a, float b, float c, float d, float s) {
  return (q8(a,s) & 255) | ((q8(b,s) & 255) << 8) | ((q8(c,s) & 255) << 16) | ((q8(d,s) & 255) << 24);
}

// Relayout W (3x [1024 n][512 k] f32) -> i8 fragments for mfma_i32_32x32x32_i8.
__global__ __launch_bounds__(256) void k_convw(const float* __restrict__ wa,
                                               const float* __restrict__ wb,
                                               const float* __restrict__ wc,
                                               char* __restrict__ out) {
  int g = blockIdx.x * 256 + threadIdx.x;   // 0..98303
  int l = g & 63;
  int blk = g >> 6;           // t*512 + nb*16 + ks
  int ks = blk & 15;
  int nb = (blk >> 4) & 31;
  int t = blk >> 9;
  const float* src = (t == 0) ? wa : (t == 1) ? wb : wc;
  int n = nb * 32 + (l & 31);
  int k0 = ks * 32 + (l >> 5) * 16;
  const f32x4* p = (const f32x4*)(src + (size_t)n * INIT_DIM + k0);
  f32x4 x0 = p[0], x1 = p[1], x2 = p[2], x3 = p[3];
  int4v v;
  v[0] = pack4(x0.x, x0.y, x0.z, x0.w, SW);
  v[1] = pack4(x1.x, x1.y, x1.z, x1.w, SW);
  v[2] = pack4(x2.x, x2.y, x2.z, x2.w, SW);
  v[3] = pack4(x3.x, x3.y, x3.z, x3.w, SW);
  *(int4v*)(out + (size_t)g * 16) = v;
}

// ---- DEDUP MACHINERY ----
// relu is positively homogeneous: sum_j relu(Wx_j+b) = sum_distinct m*relu(Wx+b).
// E[distinct] ~ 48K of 65536 per type -> 73% of tiles; sorted lists -> near-
// streaming gather; integer math makes the dedup bit-exact.

// Histogram: counts[t][node] += 1 over the 65536 neighbor samples per type.
__global__ __launch_bounds__(256) void k_hist(const int* __restrict__ na,
                                              const int* __restrict__ nb,
                                              const int* __restrict__ nc,
                                              int* __restrict__ counts) {
  int g = blockIdx.x * 256 + threadIdx.x;   // 0..196607
  int t = g >> 16, i = g & 65535;
  const int* nbr = (t == 0) ? na : (t == 1) ? nb : nc;
  atomicAdd(&counts[t * N_NODES + nbr[i]], 1);
}

// Per-256-chunk count of present nodes -> bsums[t][blk].
__global__ __launch_bounds__(256) void k_bsum(const int* __restrict__ counts,
                                              int* __restrict__ bsums) {
  __shared__ int sd[256];
  int b = blockIdx.x;                 // 0..3*391-1
  int t = b / NBLK_SC, blk = b % NBLK_SC;
  int i = blk * 256 + threadIdx.x;
  int flag = (i < N_NODES && counts[t * N_NODES + i] > 0) ? 1 : 0;
  sd[threadIdx.x] = flag;
  __syncthreads();
  for (int off = 128; off > 0; off >>= 1) {
    if (threadIdx.x < off) sd[threadIdx.x] += sd[threadIdx.x + off];
    __syncthreads();
  }
  if (threadIdx.x == 0) bsums[t * NBLK_SC + blk] = sd[0];
}

// Exclusive scan of bsums per type -> boff[t][0..390]; boff[t][391] = total.
__global__ __launch_bounds__(512) void k_scan(const int* __restrict__ bsums,
                                              int* __restrict__ boff) {
  __shared__ int sd[512];
  int tid = threadIdx.x;
  for (int t = 0; t < 3; ++t) {
    int v = (tid < NBLK_SC) ? bsums[t * NBLK_SC + tid] : 0;
    sd[tid] = v;
    __syncthreads();
    for (int off = 1; off < 512; off <<= 1) {
      int x = (tid >= off) ? sd[tid - off] : 0;
      __syncthreads();
      sd[tid] += x;
      __syncthreads();
    }
    if (tid < NBLK_SC) boff[t * 392 + tid] = sd[tid] - v;   // exclusive
    if (tid == NBLK_SC - 1) boff[t * 392 + 391] = sd[NBLK_SC - 1];  // total
    __syncthreads();
  }
}

// Scatter distinct nodes (sorted by node id) into dlist/dmult.
__global__ __launch_bounds__(256) void k_scatter(const int* __restrict__ counts,
                                                 const int* __restrict__ boff,
                                                 int* __restrict__ dlist,
                                                 int* __restrict__ dmult) {
  __shared__ int sd[256];
  int b = blockIdx.x;
  int t = b / NBLK_SC, blk = b % NBLK_SC;
  int i = blk * 256 + threadIdx.x;
  int c = (i < N_NODES) ? counts[t * N_NODES + i] : 0;
  int flag = (c > 0) ? 1 : 0;
  int tid = threadIdx.x;
  sd[tid] = flag;
  __syncthreads();
  for (int off = 1; off < 256; off <<= 1) {
    int x = (tid >= off) ? sd[tid - off] : 0;
    __syncthreads();
    sd[tid] += x;
    __syncthreads();
  }
  if (flag) {
    int pos = boff[t * 392 + blk] + sd[tid] - flag;   // exclusive local
    dlist[t * 65536 + pos] = i;
    dmult[t * 65536 + pos] = c;
  }
}

// Main: R17's proven i8 GEMM (mf=2 nf=2, 64 AGPR, 0-conflict swizzle) over
// DEDUPED sorted tiles. ~73% of tile slots are active; empty slots write
// zero partials and exit (poison-safe). Padded rows: idx 0, mult 0 -> 0.
// Epilogue weights each row by its multiplicity (exact int math).
__global__ __launch_bounds__(256) void k_main(
    const float* __restrict__ fa, const float* __restrict__ fb, const float* __restrict__ fc,
    const int* __restrict__ dlist, const int* __restrict__ dmult,
    const int* __restrict__ boff,
    const float* __restrict__ b1a, const float* __restrict__ b1b, const float* __restrict__ b1c,
    const char* __restrict__ wbf8,            // [3][32 nb][16 ks][1024B] i8 fragments
    float* __restrict__ partials) {           // [NTILE][HID]
  __shared__ __align__(16) char Asm[64 * 512];   // 32 KB
  __shared__ int mlds[64];

  int bx = blockIdx.x;
  int t = bx >> 10;
  int mtile = bx & 1023;
  int tid = threadIdx.x;

  int total = boff[t * 392 + 391];
  if (mtile * 64 >= total) {       // empty tile slot: zero partials, done
    f32x4 z = {0.f, 0.f, 0.f, 0.f};
    ((f32x4*)(partials + (size_t)bx * HID))[tid] = z;
    return;
  }

  const float* feat = (t == 0) ? fa : (t == 1) ? fb : fc;
  const float* bias = (t == 0) ? b1a : (t == 1) ? b1b : b1c;
  const char*  Wf8  = wbf8 + (size_t)t * (32 * 16 * 1024);
  const int* dl = dlist + t * 65536 + mtile * 64;
  const int* dm = dmult + t * 65536 + mtile * 64;

  int wave = tid >> 6;
  int lane = tid & 63;
  int l31 = lane & 31, hi = lane >> 5;

  if (tid < 64) mlds[tid] = dm[tid];

  // Stage: wave w -> rows {c*4+w}, lane -> 8-float chunk -> 8B i8, swizzled.
  // Rows come from the SORTED distinct list -> ascending, near-streaming.
  #pragma unroll 2
  for (int c = 0; c < 16; ++c) {
    int r = c * 4 + wave;
    int idx = dl[r];
    const float* rp = feat + (size_t)idx * INIT_DIM + lane * 8;
    f32x4 a  = *(const f32x4*)rp;
    f32x4 b2 = *((const f32x4*)rp + 1);
    int2v v;
    v[0] = pack4(a.x, a.y, a.z, a.w, SA);
    v[1] = pack4(b2.x, b2.y, b2.z, b2.w, SA);
    unsigned byte = (unsigned)r * 512u +
                    (((unsigned)lane * 8u) ^ ((unsigned)(r & 31) << 4));
    *(int2v*)(Asm + byte) = v;
  }
  __syncthreads();

  // A-read swizzle: byte = r*512 + ((ks*32 + hi*16) ^ ((r&31)<<4)).
  unsigned swz = (unsigned)l31 << 4;
  unsigned abase = (unsigned)l31 * 512u + (((unsigned)hi << 4) ^ (swz & 16u));
  unsigned swzhi = swz & 0x1E0u;

  #pragma unroll
  for (int p = 0; p < 4; ++p) {
    const char* pBa = Wf8 + ((size_t)(wave * 8 + p * 2)     << 14) + lane * 16;
    const char* pBb = Wf8 + ((size_t)(wave * 8 + p * 2 + 1) << 14) + lane * 16;

    i32x16 acc[2][2] = {};   // [mf][nf] -> 64 AGPR
    #pragma unroll 4
    for (int ks = 0; ks < 16; ++ks) {
      int4v Bf0 = *(const int4v*)(pBa + (ks << 10));
      int4v Bf1 = *(const int4v*)(pBb + (ks << 10));
      unsigned kcol = (((unsigned)ks << 5) ^ swzhi);
      int4v Af[2];
      #pragma unroll
      for (int i = 0; i < 2; ++i)
        Af[i] = *(const int4v*)(Asm + (abase + (unsigned)(i * 16384) + kcol));
      #pragma unroll
      for (int i = 0; i < 2; ++i) {
        acc[i][0] = __builtin_amdgcn_mfma_i32_32x32x32_i8(Af[i], Bf0, acc[i][0], 0, 0, 0);
        acc[i][1] = __builtin_amdgcn_mfma_i32_32x32x32_i8(Af[i], Bf1, acc[i][1], 0, 0, 0);
      }
    }

    // Multiplicity-weighted integer epilogue:
    //   s += m_row * max(acc + bq, 0);  C layout: col=l31, row=(r&3)+8*(r>>2)+4*hi+32*i.
    #pragma unroll
    for (int j = 0; j < 2; ++j) {
      int n = (wave * 8 + p * 2 + j) * 32 + l31;
      int bq = __float2int_rn(bias[n] * (SA * SW));
      int s = 0;
      #pragma unroll
      for (int i = 0; i < 2; ++i)
        #pragma unroll
        for (int r = 0; r < 16; ++r) {
          int row = (r & 3) + 8 * (r >> 2) + 4 * hi + 32 * i;
          s += mlds[row] * max(acc[i][j][r] + bq, 0);
        }
      s += __shfl_xor(s, 32);
      if (hi == 0) partials[(size_t)bx * HID + n] = (float)s * INVS;
    }
  }
}

// Reduce stage 1: coalesced f32x4 sums of 16-row slabs -> inter[192][1024].
__global__ __launch_bounds__(256) void k_reduce1(const float* __restrict__ partials,
                                                 float* __restrict__ inter) {
  int b = blockIdx.x;
  int tid = threadIdx.x;
  const f32x4* base = (const f32x4*)(partials + (size_t)b * 16 * HID) + tid;
  f32x4 s = {0.f, 0.f, 0.f, 0.f};
  #pragma unroll 4
  for (int r = 0; r < 16; ++r) {
    f32x4 v = base[r * (HID / 4)];
    s.x += v.x; s.y += v.y; s.z += v.z; s.w += v.w;
  }
  *((f32x4*)(inter + (size_t)b * HID) + tid) = s;
}

// Reduce stage 2: one 1024-thread block, col per thread.
__global__ __launch_bounds__(1024) void k_reduce2(const float* __restrict__ inter,
                                                  float* __restrict__ acc) {
  int col = threadIdx.x;
  float s = 0.f;
  #pragma unroll 8
  for (int r = 0; r < 192; ++r) s += inter[(size_t)r * HID + col];
  acc[col] = s;
}

// pooled = acc/196608 ; feat_all = relu ; logits = feat_all @ Wc.T + bc
__global__ __launch_bounds__(256) void k_final(const float* __restrict__ acc,
                                               const float* __restrict__ Wc,
                                               const float* __restrict__ bc,
                                               float* __restrict__ out) {
  __shared__ float fall[HID];
  int tid = threadIdx.x;
  const float inv = 1.f / (3.f * (float)N_NBR);
  for (int i = tid; i < HID; i += 256) {
    float p = acc[i] * inv;
    fall[i] = (p > 0.f) ? p : 0.f;
  }
  __syncthreads();
  int o = tid >> 2, q = tid & 3;
  const f32x4* w = (const f32x4*)(Wc + (size_t)o * HID + q * 256);
  const f32x4* f = (const f32x4*)(fall + q * 256);
  float s = 0.f;
  #pragma unroll 4
  for (int k = 0; k < 64; ++k) {
    f32x4 wv = w[k], fv = f[k];
    s += wv.x * fv.x + wv.y * fv.y + wv.z * fv.z + wv.w * fv.w;
  }
  s += __shfl_xor(s, 1);
  s += __shfl_xor(s, 2);
  if (q == 0) out[o] = s + bc[o];
}

extern "C" void kernel_launch(void* const* d_in, const int* in_sizes, int n_in,
                              void* d_out, int out_size, void* d_ws, size_t ws_size,
                              hipStream_t stream) {
  const float* fa  = (const float*)d_in[1];
  const int*   na  = (const int*)d_in[2];
  const float* W1a = (const float*)d_in[3];
  const float* b1a = (const float*)d_in[4];
  const float* fb  = (const float*)d_in[5];
  const int*   nb  = (const int*)d_in[6];
  const float* W1b = (const float*)d_in[7];
  const float* b1b = (const float*)d_in[8];
  const float* fc  = (const float*)d_in[9];
  const int*   nc  = (const int*)d_in[10];
  const float* W1c = (const float*)d_in[11];
  const float* b1c = (const float*)d_in[12];
  const float* Wc  = (const float*)d_in[13];
  const float* bc  = (const float*)d_in[14];
  float* out = (float*)d_out;

  // ws layout (4KB-aligned chunks)
  char* base = (char*)d_ws;
  float* acc   = (float*)base;                                   // 4 KB
  char*  wbf8  = base + 4096;                                    // 1.5 MB
  int*   counts = (int*)(base + 4096 + 1572864);                 // 1.2 MB (3x100000)
  int*   bsums  = (int*)((char*)counts + 1204224);               // 8 KB region
  int*   boff   = (int*)((char*)bsums + 8192);                   // 8 KB region
  int*   dlist  = (int*)((char*)boff + 8192);                    // 768 KB
  int*   dmult  = (int*)((char*)dlist + 786432);                 // 768 KB
  float* partials = (float*)((char*)dmult + 786432);             // 12.6 MB
  float* inter = partials + (size_t)NTILE * HID;                 // 768 KB

  k_convw<<<384, 256, 0, stream>>>(W1a, W1b, W1c, wbf8);

  // Dedup: zero counts + padded lists, histogram, scan, scatter (sorted).
  hipMemsetAsync(counts, 0, 3 * N_NODES * sizeof(int), stream);
  hipMemsetAsync(dlist, 0, 3 * 65536 * sizeof(int), stream);
  hipMemsetAsync(dmult, 0, 3 * 65536 * sizeof(int), stream);
  k_hist<<<768, 256, 0, stream>>>(na, nb, nc, counts);
  k_bsum<<<3 * NBLK_SC, 256, 0, stream>>>(counts, bsums);
  k_scan<<<1, 512, 0, stream>>>(bsums, boff);
  k_scatter<<<3 * NBLK_SC, 256, 0, stream>>>(counts, boff, dlist, dmult);

  k_main<<<NTILE, 256, 0, stream>>>(fa, fb, fc, dlist, dmult, boff,
                                    b1a, b1b, b1c, wbf8, partials);
  k_reduce1<<<192, 256, 0, stream>>>(partials, inter);
  k_reduce2<<<1, 1024, 0, stream>>>(inter, acc);
  k_final<<<1, 256, 0, stream>>>(acc, Wc, bc, out);
}